// Round 3
// baseline (310.886 us; speedup 1.0000x reference)
//
#include <hip/hip_runtime.h>

// TinyAttention on MI355X: b=4, t=2048, d=1024, single head.
// R3: all GEMMs switched 16x16x32 -> 32x32x16 bf16 MFMA (m119: 2495 vs 2176 TF).
// m97-style 128x128 tile, BK=32, global_load_lds(16B), 4 waves x 64x64/wave.

typedef __bf16 bf16x8_t __attribute__((ext_vector_type(8)));
typedef float  f32x16_t __attribute__((ext_vector_type(16)));
typedef unsigned short u16;

struct alignas(8) u16x4 { u16 x, y, z, w; };

__device__ inline float bf2f(u16 u) {
  union { unsigned u; float f; } c; c.u = ((unsigned)u) << 16; return c.f;
}
__device__ inline u16 f2bf(float f) {  // round-to-nearest-even
  union { float f; unsigned u; } c; c.f = f;
  unsigned r = c.u + 0x7fffu + ((c.u >> 16) & 1u);
  return (u16)(r >> 16);
}

// OUTMODE: 0 = bf16 row-major, 1 = f32 row-major + bias, 2 = QKV split
//          (bn0<2048 -> qk row-major bf16; bn0>=2048 -> vT col-major bf16)
// GRIDMODE: 0 = normal, 1 = compact lower-triangular, 2 = reversed-y + K<=bm0+128
template<int OUTMODE, int GRIDMODE>
__global__ __launch_bounds__(256)
void gemm_bt(const u16* __restrict__ A, const u16* __restrict__ B,
             void* __restrict__ Cv, u16* __restrict__ C2,
             const float* __restrict__ bias,
             int K, int lda, int ldb, int ldc,
             long sA, long sB, long sC)
{
  int bn0, bm0;
  if (GRIDMODE == 1) {
    const int x = blockIdx.x;                       // 0..135
    int r = (int)((sqrtf(8.f * x + 1.f) - 1.f) * 0.5f);
    while ((r + 1) * (r + 2) / 2 <= x) ++r;
    while (r * (r + 1) / 2 > x) --r;
    bm0 = r * 128;
    bn0 = (x - r * (r + 1) / 2) * 128;
  } else if (GRIDMODE == 2) {
    bn0 = blockIdx.x * 128;
    bm0 = ((int)gridDim.y - 1 - (int)blockIdx.y) * 128;  // longest K first
  } else {
    bn0 = blockIdx.x * 128;
    bm0 = blockIdx.y * 128;
  }
  const long bz = blockIdx.z;
  const u16* Ab = A + bz * sA;
  const u16* Bb = B + bz * sB;
  const int Keff = (GRIDMODE == 2) ? min(K, bm0 + 128) : K;

  __shared__ __align__(16) u16 lA[128 * 32];
  __shared__ __align__(16) u16 lB[128 * 32];

  const int tid  = threadIdx.x;
  const int lane = tid & 63;
  const int wv   = tid >> 6;
  const int wm   = (wv >> 1) << 6;   // wave's 64-row offset
  const int wn   = (wv & 1) << 6;    // wave's 64-col offset
  const int ml   = lane & 31;        // A-row / B-col / D-col within 32-tile
  const int kh   = lane >> 5;        // k-half 0..1

  f32x16_t acc[2][2];
#pragma unroll
  for (int i = 0; i < 2; ++i)
#pragma unroll
    for (int j = 0; j < 2; ++j)
#pragma unroll
      for (int r = 0; r < 16; ++r)
        acc[i][j][r] = 0.f;

  // per-thread staging base pointers (hoisted out of K-loop)
  const char* gA = (const char*)(Ab + (long)bm0 * lda);
  const char* gB = (const char*)(Bb + (long)bn0 * ldb);
  const int bo0 = tid * 16, bo1 = (256 + tid) * 16;   // LDS byte offsets
  const int row0 = bo0 >> 6, cb0 = bo0 & 63;          // 64B per 32-elem row
  const int row1 = bo1 >> 6, cb1 = bo1 & 63;
  const char* pA0 = gA + (long)row0 * (lda * 2) + cb0;
  const char* pA1 = gA + (long)row1 * (lda * 2) + cb1;
  const char* pB0 = gB + (long)row0 * (ldb * 2) + cb0;
  const char* pB1 = gB + (long)row1 * (ldb * 2) + cb1;

  for (int k0 = 0; k0 < Keff; k0 += 32) {
    const long kb = (long)k0 * 2;
    __builtin_amdgcn_global_load_lds(
        (const __attribute__((address_space(1))) unsigned int*)(pA0 + kb),
        (__attribute__((address_space(3))) unsigned int*)((char*)lA + bo0), 16, 0, 0);
    __builtin_amdgcn_global_load_lds(
        (const __attribute__((address_space(1))) unsigned int*)(pB0 + kb),
        (__attribute__((address_space(3))) unsigned int*)((char*)lB + bo0), 16, 0, 0);
    __builtin_amdgcn_global_load_lds(
        (const __attribute__((address_space(1))) unsigned int*)(pA1 + kb),
        (__attribute__((address_space(3))) unsigned int*)((char*)lA + bo1), 16, 0, 0);
    __builtin_amdgcn_global_load_lds(
        (const __attribute__((address_space(1))) unsigned int*)(pB1 + kb),
        (__attribute__((address_space(3))) unsigned int*)((char*)lB + bo1), 16, 0, 0);
    __syncthreads();

    // A frag: m=ml, k=kh*8+j  (gfx950 contiguous-8); two 32-row tiles, two k-halves
    bf16x8_t af[2][2], bfr[2][2];
#pragma unroll
    for (int i = 0; i < 2; ++i)
#pragma unroll
      for (int s = 0; s < 2; ++s)
        af[i][s] = *(const bf16x8_t*)&lA[(wm + i * 32 + ml) * 32 + s * 16 + kh * 8];
#pragma unroll
    for (int j = 0; j < 2; ++j)
#pragma unroll
      for (int s = 0; s < 2; ++s)
        bfr[j][s] = *(const bf16x8_t*)&lB[(wn + j * 32 + ml) * 32 + s * 16 + kh * 8];
#pragma unroll
    for (int i = 0; i < 2; ++i)
#pragma unroll
      for (int j = 0; j < 2; ++j) {
        acc[i][j] = __builtin_amdgcn_mfma_f32_32x32x16_bf16(af[i][0], bfr[j][0], acc[i][j], 0, 0, 0);
        acc[i][j] = __builtin_amdgcn_mfma_f32_32x32x16_bf16(af[i][1], bfr[j][1], acc[i][j], 0, 0, 0);
      }
    __syncthreads();
  }

  // epilogue: 32x32 D layout col=lane&31, row=(reg&3)+8*(reg>>2)+4*(lane>>5)
  if (OUTMODE == 2 && bn0 >= 2048) {
    // V columns: write vT[batch][dcol][s] col-major, u16x4 over 4 consecutive rows
#pragma unroll
    for (int i = 0; i < 2; ++i) {
#pragma unroll
      for (int g = 0; g < 4; ++g) {
        const int rowb = bm0 + wm + i * 32 + g * 8 + kh * 4;  // 4 consecutive M rows
        const int b_  = rowb >> 11;                            // batch (t=2048)
        const int s_  = rowb & 2047;
#pragma unroll
        for (int j = 0; j < 2; ++j) {
          const int dcol = bn0 - 2048 + wn + j * 32 + ml;
          u16x4 o = {f2bf(acc[i][j][g * 4 + 0]), f2bf(acc[i][j][g * 4 + 1]),
                     f2bf(acc[i][j][g * 4 + 2]), f2bf(acc[i][j][g * 4 + 3])};
          *(u16x4*)&C2[(((long)b_ * 1024 + dcol) << 11) + s_] = o;
        }
      }
    }
    return;
  }
  u16*   Cb16 = (u16*)Cv + bz * sC;
  float* Cf32 = (float*)Cv + bz * sC;
#pragma unroll
  for (int i = 0; i < 2; ++i) {
#pragma unroll
    for (int j = 0; j < 2; ++j) {
#pragma unroll
      for (int reg = 0; reg < 16; ++reg) {
        const int row = bm0 + wm + i * 32 + (reg & 3) + 8 * (reg >> 2) + kh * 4;
        const int col = bn0 + wn + j * 32 + ml;
        float v = acc[i][j][reg];
        if (OUTMODE == 1) {
          Cf32[(long)row * ldc + col] = v + bias[col];
        } else {
          Cb16[(long)row * ldc + col] = f2bf(v);
        }
      }
    }
  }
}

// ---------------------------------------------------------------------------
__global__ __launch_bounds__(256)
void cvt_f32_bf16(const float* __restrict__ in, u16* __restrict__ out) {
  const int i = blockIdx.x * 256 + threadIdx.x;
  float4 v = ((const float4*)in)[i];
  u16x4 o = {f2bf(v.x), f2bf(v.y), f2bf(v.z), f2bf(v.w)};
  ((u16x4*)out)[i] = o;
}

// both weight transposes in one dispatch
__global__ __launch_bounds__(256)
void transpose_weights(const float* __restrict__ wqkv, u16* __restrict__ wqkvT,
                       const float* __restrict__ wproj, u16* __restrict__ wprojT) {
  const bool isq = blockIdx.x < 96;
  const float* in = isq ? wqkv : wproj;
  u16* out        = isq ? wqkvT : wprojT;
  const int C     = isq ? 3072 : 1024;
  const int c0 = (isq ? blockIdx.x : (blockIdx.x - 96)) * 32;
  const int r0 = blockIdx.y * 32;
  __shared__ float t[32][33];
  const int tx = threadIdx.x & 31, ty = threadIdx.x >> 5;
#pragma unroll
  for (int i = 0; i < 32; i += 8)
    t[ty + i][tx] = in[(long)(r0 + ty + i) * C + (c0 + tx)];
  __syncthreads();
#pragma unroll
  for (int i = 0; i < 32; i += 8)
    out[(long)(c0 + ty + i) * 1024 + (r0 + tx)] = f2bf(t[tx][ty + i]);
}

// ---------------------------------------------------------------------------
// Causal row softmax, in-place bf16 S -> P, register-resident.
// 256 threads x 8 elements = 2048 row. Applies 1/32 scale; zero-fills
// [len, 128-aligned end) so PV's K-limit reads only valid data.
// ---------------------------------------------------------------------------
__global__ __launch_bounds__(256)
void softmax_causal(u16* __restrict__ SP) {
  const int t = blockIdx.x;
  const int b = blockIdx.y;
  u16* row = SP + ((long)b * 2048 + t) * 2048;
  const int len = t + 1;
  const int end = ((t >> 7) + 1) << 7;   // 128-aligned
  const int tid = threadIdx.x;
  const int s0  = tid * 8;
  const float scale = 0.03125f;          // 1/sqrt(1024)
  __shared__ float red[8];

  float v[8];
  float lmax = -3.0e38f;
  if (s0 < end) {
    u16x4 u0 = *(const u16x4*)(row + s0);
    u16x4 u1 = *(const u16x4*)(row + s0 + 4);
    v[0] = bf2f(u0.x); v[1] = bf2f(u0.y); v[2] = bf2f(u0.z); v[3] = bf2f(u0.w);
    v[4] = bf2f(u1.x); v[5] = bf2f(u1.y); v[6] = bf2f(u1.z); v[7] = bf2f(u1.w);
#pragma unroll
    for (int e = 0; e < 8; ++e)
      if (s0 + e < len) { v[e] *= scale; lmax = fmaxf(lmax, v[e]); }
  }
#pragma unroll
  for (int o = 32; o; o >>= 1) lmax = fmaxf(lmax, __shfl_down(lmax, o));
  if ((tid & 63) == 0) red[tid >> 6] = lmax;
  __syncthreads();
  const float m = fmaxf(fmaxf(red[0], red[1]), fmaxf(red[2], red[3]));

  float lsum = 0.f;
  if (s0 < len) {
#pragma unroll
    for (int e = 0; e < 8; ++e)
      if (s0 + e < len) { v[e] = __expf(v[e] - m); lsum += v[e]; }
  }
#pragma unroll
  for (int o = 32; o; o >>= 1) lsum += __shfl_down(lsum, o);
  if ((tid & 63) == 0) red[4 + (tid >> 6)] = lsum;
  __syncthreads();
  const float inv = 1.0f / (red[4] + red[5] + red[6] + red[7]);

  if (s0 < end) {
    u16x4 o0, o1;
#pragma unroll
    for (int e = 0; e < 8; ++e) {
      const float ve = (s0 + e < len) ? v[e] * inv : 0.f;
      if (e < 4) ((u16*)&o0)[e] = f2bf(ve);
      else       ((u16*)&o1)[e - 4] = f2bf(ve);
    }
    *(u16x4*)(row + s0)     = o0;
    *(u16x4*)(row + s0 + 4) = o1;
  }
}

// ---------------------------------------------------------------------------
extern "C" void kernel_launch(void* const* d_in, const int* in_sizes, int n_in,
                              void* d_out, int out_size, void* d_ws, size_t ws_size,
                              hipStream_t stream) {
  (void)in_sizes; (void)n_in; (void)out_size; (void)ws_size;
  const float* x      = (const float*)d_in[0];
  const float* w_qkv  = (const float*)d_in[1];
  const float* w_proj = (const float*)d_in[2];
  const float* b_proj = (const float*)d_in[3];
  float* y = (float*)d_out;
  char*  ws = (char*)d_ws;

  // workspace layout (104 MB)
  u16* xbf    = (u16*)(ws);                  // 16 MB  x bf16; reused for attn_out
  u16* qk     = (u16*)(ws + (16l << 20));    // 32 MB  [4][2048][2048] bf16 (q | k)
  u16* wqkvT  = (u16*)(ws + (48l << 20));    //  6 MB  [3072,1024]
  u16* wprojT = (u16*)(ws + (54l << 20));    //  2 MB  [1024,1024]
  u16* vT     = (u16*)(ws + (56l << 20));    // 16 MB  [4][1024][2048]
  u16* SP     = (u16*)(ws + (72l << 20));    // 32 MB  [4][2048][2048] S->P in place
  u16* attn   = xbf;                         // lifetime-disjoint reuse

  // 1) x -> bf16
  cvt_f32_bf16<<<8192, 256, 0, stream>>>(x, xbf);
  // 2) weights -> transposed bf16 (one dispatch)
  transpose_weights<<<dim3(128, 32), 256, 0, stream>>>(w_qkv, wqkvT, w_proj, wprojT);
  // 3) qkv = x @ w_qkv : M=8192 N=3072 K=1024; q,k -> qk (ldc 2048), v -> vT fused
  gemm_bt<2, 0><<<dim3(24, 64, 1), 256, 0, stream>>>(
      xbf, wqkvT, qk, vT, nullptr, 1024, 1024, 1024, 2048, 0, 0, 0);
  // 4) S = q @ k^T, compact lower-triangular grid: 136 blocks x 4 batches
  gemm_bt<0, 1><<<dim3(136, 1, 4), 256, 0, stream>>>(
      qk, qk + 1024, SP, nullptr, nullptr, 1024, 2048, 2048, 2048,
      (long)2048 * 2048, (long)2048 * 2048, (long)2048 * 2048);
  // 5) P = softmax(S / 32), causal, in place, register-resident
  softmax_causal<<<dim3(2048, 4), 256, 0, stream>>>(SP);
  // 6) attn = P @ V : K_eff = bm0+128, longest blocks dispatched first
  gemm_bt<0, 2><<<dim3(8, 16, 4), 256, 0, stream>>>(
      SP, vT, attn, nullptr, nullptr, 2048, 2048, 2048, 1024,
      (long)2048 * 2048, (long)1024 * 2048, (long)2048 * 1024);
  // 7) y = attn @ w_proj + b_proj : fp32 out
  gemm_bt<1, 0><<<dim3(8, 64, 1), 256, 0, stream>>>(
      attn, wprojT, y, nullptr, b_proj, 1024, 1024, 1024, 1024, 0, 0, 0);
}

// Round 4
// 304.828 us; speedup vs baseline: 1.0199x; 1.0199x over previous
//
#include <hip/hip_runtime.h>

// TinyAttention on MI355X: b=4, t=2048, d=1024, single head.
// R4: XOR-swizzled LDS (chunk16 ^= row&3) to fix the 32x32-fragment bank
// conflicts found in R3 (18.9M SQ_LDS_BANK_CONFLICT -> expect ~0).
// 32x32x16 bf16 MFMA, 128x128 tile, BK=32, global_load_lds(16B).

typedef __bf16 bf16x8_t __attribute__((ext_vector_type(8)));
typedef float  f32x16_t __attribute__((ext_vector_type(16)));
typedef unsigned short u16;

struct alignas(8) u16x4 { u16 x, y, z, w; };

__device__ inline float bf2f(u16 u) {
  union { unsigned u; float f; } c; c.u = ((unsigned)u) << 16; return c.f;
}
__device__ inline u16 f2bf(float f) {  // round-to-nearest-even
  union { float f; unsigned u; } c; c.f = f;
  unsigned r = c.u + 0x7fffu + ((c.u >> 16) & 1u);
  return (u16)(r >> 16);
}

// OUTMODE: 0 = bf16 row-major, 1 = f32 row-major + bias, 2 = QKV split
//          (bn0<2048 -> qk row-major bf16; bn0>=2048 -> vT col-major bf16)
// GRIDMODE: 0 = normal, 1 = compact lower-triangular, 2 = reversed-y + K<=bm0+128
template<int OUTMODE, int GRIDMODE>
__global__ __launch_bounds__(256)
void gemm_bt(const u16* __restrict__ A, const u16* __restrict__ B,
             void* __restrict__ Cv, u16* __restrict__ C2,
             const float* __restrict__ bias,
             int K, int lda, int ldb, int ldc,
             long sA, long sB, long sC)
{
  int bn0, bm0;
  if (GRIDMODE == 1) {
    const int x = blockIdx.x;                       // 0..135
    int r = (int)((sqrtf(8.f * x + 1.f) - 1.f) * 0.5f);
    while ((r + 1) * (r + 2) / 2 <= x) ++r;
    while (r * (r + 1) / 2 > x) --r;
    bm0 = r * 128;
    bn0 = (x - r * (r + 1) / 2) * 128;
  } else if (GRIDMODE == 2) {
    bn0 = blockIdx.x * 128;
    bm0 = ((int)gridDim.y - 1 - (int)blockIdx.y) * 128;  // longest K first
  } else {
    bn0 = blockIdx.x * 128;
    bm0 = blockIdx.y * 128;
  }
  const long bz = blockIdx.z;
  const u16* Ab = A + bz * sA;
  const u16* Bb = B + bz * sB;
  const int Keff = (GRIDMODE == 2) ? min(K, bm0 + 128) : K;

  __shared__ __align__(16) u16 lA[128 * 32];
  __shared__ __align__(16) u16 lB[128 * 32];

  const int tid  = threadIdx.x;
  const int lane = tid & 63;
  const int wv   = tid >> 6;
  const int wm   = (wv >> 1) << 6;   // wave's 64-row offset
  const int wn   = (wv & 1) << 6;    // wave's 64-col offset
  const int ml   = lane & 31;        // A-row / B-col / D-col within 32-tile
  const int kh   = lane >> 5;        // k-half 0..1
  const int swz  = ml & 3;           // row-derived chunk16 XOR swizzle

  f32x16_t acc[2][2];
#pragma unroll
  for (int i = 0; i < 2; ++i)
#pragma unroll
    for (int j = 0; j < 2; ++j)
#pragma unroll
      for (int r = 0; r < 16; ++r)
        acc[i][j][r] = 0.f;

  // Staging: LDS chunk16 (row, c) stores global chunk (row, c ^ (row&3)).
  // Dest LDS offsets are lane-contiguous (HW requirement); the permutation
  // is applied to the per-lane global source address.
  const char* gA = (const char*)(Ab + (long)bm0 * lda);
  const char* gB = (const char*)(Bb + (long)bn0 * ldb);
  const int bo0 = tid * 16, bo1 = (256 + tid) * 16;   // LDS byte offsets
  const int ch0 = bo0 >> 4,  ch1 = bo1 >> 4;          // chunk16 index
  const int row0 = ch0 >> 2, row1 = ch1 >> 2;         // 4 chunk16 per row
  const int cb0 = ((ch0 & 3) ^ (row0 & 3)) << 4;      // swizzled byte-in-row
  const int cb1 = ((ch1 & 3) ^ (row1 & 3)) << 4;
  const char* pA0 = gA + (long)row0 * (lda * 2) + cb0;
  const char* pA1 = gA + (long)row1 * (lda * 2) + cb1;
  const char* pB0 = gB + (long)row0 * (ldb * 2) + cb0;
  const char* pB1 = gB + (long)row1 * (ldb * 2) + cb1;

  for (int k0 = 0; k0 < Keff; k0 += 32) {
    const long kb = (long)k0 * 2;
    __builtin_amdgcn_global_load_lds(
        (const __attribute__((address_space(1))) unsigned int*)(pA0 + kb),
        (__attribute__((address_space(3))) unsigned int*)((char*)lA + bo0), 16, 0, 0);
    __builtin_amdgcn_global_load_lds(
        (const __attribute__((address_space(1))) unsigned int*)(pB0 + kb),
        (__attribute__((address_space(3))) unsigned int*)((char*)lB + bo0), 16, 0, 0);
    __builtin_amdgcn_global_load_lds(
        (const __attribute__((address_space(1))) unsigned int*)(pA1 + kb),
        (__attribute__((address_space(3))) unsigned int*)((char*)lA + bo1), 16, 0, 0);
    __builtin_amdgcn_global_load_lds(
        (const __attribute__((address_space(1))) unsigned int*)(pB1 + kb),
        (__attribute__((address_space(3))) unsigned int*)((char*)lB + bo1), 16, 0, 0);
    __syncthreads();

    // A frag (row, k-chunk s*2+kh) lives at LDS chunk (s*2+kh) ^ (row&3)
    bf16x8_t af[2][2], bfr[2][2];
#pragma unroll
    for (int i = 0; i < 2; ++i)
#pragma unroll
      for (int s = 0; s < 2; ++s)
        af[i][s] = *(const bf16x8_t*)&lA[(wm + i * 32 + ml) * 32 + (((s * 2 + kh) ^ swz) << 3)];
#pragma unroll
    for (int j = 0; j < 2; ++j)
#pragma unroll
      for (int s = 0; s < 2; ++s)
        bfr[j][s] = *(const bf16x8_t*)&lB[(wn + j * 32 + ml) * 32 + (((s * 2 + kh) ^ swz) << 3)];
#pragma unroll
    for (int i = 0; i < 2; ++i)
#pragma unroll
      for (int j = 0; j < 2; ++j) {
        acc[i][j] = __builtin_amdgcn_mfma_f32_32x32x16_bf16(af[i][0], bfr[j][0], acc[i][j], 0, 0, 0);
        acc[i][j] = __builtin_amdgcn_mfma_f32_32x32x16_bf16(af[i][1], bfr[j][1], acc[i][j], 0, 0, 0);
      }
    __syncthreads();
  }

  // epilogue: 32x32 D layout col=lane&31, row=(reg&3)+8*(reg>>2)+4*(lane>>5)
  if (OUTMODE == 2 && bn0 >= 2048) {
    // V columns: write vT[batch][dcol][s] col-major, u16x4 over 4 consecutive rows
#pragma unroll
    for (int i = 0; i < 2; ++i) {
#pragma unroll
      for (int g = 0; g < 4; ++g) {
        const int rowb = bm0 + wm + i * 32 + g * 8 + kh * 4;  // 4 consecutive M rows
        const int b_  = rowb >> 11;                            // batch (t=2048)
        const int s_  = rowb & 2047;
#pragma unroll
        for (int j = 0; j < 2; ++j) {
          const int dcol = bn0 - 2048 + wn + j * 32 + ml;
          u16x4 o = {f2bf(acc[i][j][g * 4 + 0]), f2bf(acc[i][j][g * 4 + 1]),
                     f2bf(acc[i][j][g * 4 + 2]), f2bf(acc[i][j][g * 4 + 3])};
          *(u16x4*)&C2[(((long)b_ * 1024 + dcol) << 11) + s_] = o;
        }
      }
    }
    return;
  }
  u16*   Cb16 = (u16*)Cv + bz * sC;
  float* Cf32 = (float*)Cv + bz * sC;
#pragma unroll
  for (int i = 0; i < 2; ++i) {
#pragma unroll
    for (int j = 0; j < 2; ++j) {
#pragma unroll
      for (int reg = 0; reg < 16; ++reg) {
        const int row = bm0 + wm + i * 32 + (reg & 3) + 8 * (reg >> 2) + kh * 4;
        const int col = bn0 + wn + j * 32 + ml;
        float v = acc[i][j][reg];
        if (OUTMODE == 1) {
          Cf32[(long)row * ldc + col] = v + bias[col];
        } else {
          Cb16[(long)row * ldc + col] = f2bf(v);
        }
      }
    }
  }
}

// ---------------------------------------------------------------------------
__global__ __launch_bounds__(256)
void cvt_f32_bf16(const float* __restrict__ in, u16* __restrict__ out) {
  const int i = blockIdx.x * 256 + threadIdx.x;
  float4 v = ((const float4*)in)[i];
  u16x4 o = {f2bf(v.x), f2bf(v.y), f2bf(v.z), f2bf(v.w)};
  ((u16x4*)out)[i] = o;
}

// both weight transposes in one dispatch
__global__ __launch_bounds__(256)
void transpose_weights(const float* __restrict__ wqkv, u16* __restrict__ wqkvT,
                       const float* __restrict__ wproj, u16* __restrict__ wprojT) {
  const bool isq = blockIdx.x < 96;
  const float* in = isq ? wqkv : wproj;
  u16* out        = isq ? wqkvT : wprojT;
  const int C     = isq ? 3072 : 1024;
  const int c0 = (isq ? blockIdx.x : (blockIdx.x - 96)) * 32;
  const int r0 = blockIdx.y * 32;
  __shared__ float t[32][33];
  const int tx = threadIdx.x & 31, ty = threadIdx.x >> 5;
#pragma unroll
  for (int i = 0; i < 32; i += 8)
    t[ty + i][tx] = in[(long)(r0 + ty + i) * C + (c0 + tx)];
  __syncthreads();
#pragma unroll
  for (int i = 0; i < 32; i += 8)
    out[(long)(c0 + ty + i) * 1024 + (r0 + tx)] = f2bf(t[tx][ty + i]);
}

// ---------------------------------------------------------------------------
// Causal row softmax, in-place bf16 S -> P, register-resident.
// ---------------------------------------------------------------------------
__global__ __launch_bounds__(256)
void softmax_causal(u16* __restrict__ SP) {
  const int t = blockIdx.x;
  const int b = blockIdx.y;
  u16* row = SP + ((long)b * 2048 + t) * 2048;
  const int len = t + 1;
  const int end = ((t >> 7) + 1) << 7;   // 128-aligned
  const int tid = threadIdx.x;
  const int s0  = tid * 8;
  const float scale = 0.03125f;          // 1/sqrt(1024)
  __shared__ float red[8];

  float v[8];
  float lmax = -3.0e38f;
  if (s0 < end) {
    u16x4 u0 = *(const u16x4*)(row + s0);
    u16x4 u1 = *(const u16x4*)(row + s0 + 4);
    v[0] = bf2f(u0.x); v[1] = bf2f(u0.y); v[2] = bf2f(u0.z); v[3] = bf2f(u0.w);
    v[4] = bf2f(u1.x); v[5] = bf2f(u1.y); v[6] = bf2f(u1.z); v[7] = bf2f(u1.w);
#pragma unroll
    for (int e = 0; e < 8; ++e)
      if (s0 + e < len) { v[e] *= scale; lmax = fmaxf(lmax, v[e]); }
  }
#pragma unroll
  for (int o = 32; o; o >>= 1) lmax = fmaxf(lmax, __shfl_down(lmax, o));
  if ((tid & 63) == 0) red[tid >> 6] = lmax;
  __syncthreads();
  const float m = fmaxf(fmaxf(red[0], red[1]), fmaxf(red[2], red[3]));

  float lsum = 0.f;
  if (s0 < len) {
#pragma unroll
    for (int e = 0; e < 8; ++e)
      if (s0 + e < len) { v[e] = __expf(v[e] - m); lsum += v[e]; }
  }
#pragma unroll
  for (int o = 32; o; o >>= 1) lsum += __shfl_down(lsum, o);
  if ((tid & 63) == 0) red[4 + (tid >> 6)] = lsum;
  __syncthreads();
  const float inv = 1.0f / (red[4] + red[5] + red[6] + red[7]);

  if (s0 < end) {
    u16x4 o0, o1;
#pragma unroll
    for (int e = 0; e < 8; ++e) {
      const float ve = (s0 + e < len) ? v[e] * inv : 0.f;
      if (e < 4) ((u16*)&o0)[e] = f2bf(ve);
      else       ((u16*)&o1)[e - 4] = f2bf(ve);
    }
    *(u16x4*)(row + s0)     = o0;
    *(u16x4*)(row + s0 + 4) = o1;
  }
}

// ---------------------------------------------------------------------------
extern "C" void kernel_launch(void* const* d_in, const int* in_sizes, int n_in,
                              void* d_out, int out_size, void* d_ws, size_t ws_size,
                              hipStream_t stream) {
  (void)in_sizes; (void)n_in; (void)out_size; (void)ws_size;
  const float* x      = (const float*)d_in[0];
  const float* w_qkv  = (const float*)d_in[1];
  const float* w_proj = (const float*)d_in[2];
  const float* b_proj = (const float*)d_in[3];
  float* y = (float*)d_out;
  char*  ws = (char*)d_ws;

  // workspace layout (104 MB)
  u16* xbf    = (u16*)(ws);                  // 16 MB  x bf16; reused for attn_out
  u16* qk     = (u16*)(ws + (16l << 20));    // 32 MB  [4][2048][2048] bf16 (q | k)
  u16* wqkvT  = (u16*)(ws + (48l << 20));    //  6 MB  [3072,1024]
  u16* wprojT = (u16*)(ws + (54l << 20));    //  2 MB  [1024,1024]
  u16* vT     = (u16*)(ws + (56l << 20));    // 16 MB  [4][1024][2048]
  u16* SP     = (u16*)(ws + (72l << 20));    // 32 MB  [4][2048][2048] S->P in place
  u16* attn   = xbf;                         // lifetime-disjoint reuse

  // 1) x -> bf16
  cvt_f32_bf16<<<8192, 256, 0, stream>>>(x, xbf);
  // 2) weights -> transposed bf16 (one dispatch)
  transpose_weights<<<dim3(128, 32), 256, 0, stream>>>(w_qkv, wqkvT, w_proj, wprojT);
  // 3) qkv = x @ w_qkv : M=8192 N=3072 K=1024; q,k -> qk (ldc 2048), v -> vT fused
  gemm_bt<2, 0><<<dim3(24, 64, 1), 256, 0, stream>>>(
      xbf, wqkvT, qk, vT, nullptr, 1024, 1024, 1024, 2048, 0, 0, 0);
  // 4) S = q @ k^T, compact lower-triangular grid: 136 blocks x 4 batches
  gemm_bt<0, 1><<<dim3(136, 1, 4), 256, 0, stream>>>(
      qk, qk + 1024, SP, nullptr, nullptr, 1024, 2048, 2048, 2048,
      (long)2048 * 2048, (long)2048 * 2048, (long)2048 * 2048);
  // 5) P = softmax(S / 32), causal, in place, register-resident
  softmax_causal<<<dim3(2048, 4), 256, 0, stream>>>(SP);
  // 6) attn = P @ V : K_eff = bm0+128, longest blocks dispatched first
  gemm_bt<0, 2><<<dim3(8, 16, 4), 256, 0, stream>>>(
      SP, vT, attn, nullptr, nullptr, 2048, 2048, 2048, 1024,
      (long)2048 * 2048, (long)1024 * 2048, (long)2048 * 1024);
  // 7) y = attn @ w_proj + b_proj : fp32 out
  gemm_bt<1, 0><<<dim3(8, 64, 1), 256, 0, stream>>>(
      attn, wprojT, y, nullptr, b_proj, 1024, 1024, 1024, 1024, 0, 0, 0);
}

// Round 5
// 285.370 us; speedup vs baseline: 1.0894x; 1.0682x over previous
//
#include <hip/hip_runtime.h>

// TinyAttention on MI355X: b=4, t=2048, d=1024, single head.
// R5: stall-bound fixes — __launch_bounds__(256,4) for 4 blocks/CU,
// BK=64 (halve barrier drains), correct full-3-bit XOR LDS swizzle.
// 32x32x16 bf16 MFMA, 128x128 tile, global_load_lds(16B).

typedef __bf16 bf16x8_t __attribute__((ext_vector_type(8)));
typedef float  f32x16_t __attribute__((ext_vector_type(16)));
typedef unsigned short u16;

struct alignas(8) u16x4 { u16 x, y, z, w; };

__device__ inline float bf2f(u16 u) {
  union { unsigned u; float f; } c; c.u = ((unsigned)u) << 16; return c.f;
}
__device__ inline u16 f2bf(float f) {  // round-to-nearest-even
  union { float f; unsigned u; } c; c.f = f;
  unsigned r = c.u + 0x7fffu + ((c.u >> 16) & 1u);
  return (u16)(r >> 16);
}

// OUTMODE: 0 = bf16 row-major, 1 = f32 row-major + bias, 2 = QKV split
//          (bn0<2048 -> qk row-major bf16; bn0>=2048 -> vT col-major bf16)
// GRIDMODE: 0 = normal, 1 = compact lower-triangular, 2 = reversed-y + K<=bm0+128
template<int OUTMODE, int GRIDMODE>
__global__ __launch_bounds__(256, 4)
void gemm_bt(const u16* __restrict__ A, const u16* __restrict__ B,
             void* __restrict__ Cv, u16* __restrict__ C2,
             const float* __restrict__ bias,
             int K, int lda, int ldb, int ldc,
             long sA, long sB, long sC)
{
  int bn0, bm0;
  if (GRIDMODE == 1) {
    const int x = blockIdx.x;                       // 0..135
    int r = (int)((sqrtf(8.f * x + 1.f) - 1.f) * 0.5f);
    while ((r + 1) * (r + 2) / 2 <= x) ++r;
    while (r * (r + 1) / 2 > x) --r;
    bm0 = r * 128;
    bn0 = (x - r * (r + 1) / 2) * 128;
  } else if (GRIDMODE == 2) {
    bn0 = blockIdx.x * 128;
    bm0 = ((int)gridDim.y - 1 - (int)blockIdx.y) * 128;  // longest K first
  } else {
    bn0 = blockIdx.x * 128;
    bm0 = blockIdx.y * 128;
  }
  const long bz = blockIdx.z;
  const u16* Ab = A + bz * sA;
  const u16* Bb = B + bz * sB;
  const int Keff = (GRIDMODE == 2) ? min(K, bm0 + 128) : K;

  // BK=64: 128 rows x 64 u16 = 16 KB per matrix, 32 KB total
  __shared__ __align__(16) u16 lA[128 * 64];
  __shared__ __align__(16) u16 lB[128 * 64];

  const int tid  = threadIdx.x;
  const int lane = tid & 63;
  const int wv   = tid >> 6;
  const int wm   = (wv >> 1) << 6;   // wave's 64-row offset
  const int wn   = (wv & 1) << 6;    // wave's 64-col offset
  const int ml   = lane & 31;        // A-row / B-col / D-col within 32-tile
  const int kh   = lane >> 5;        // k-half 0..1
  const int swz  = ml & 7;           // full 3-bit row-derived chunk16 XOR

  f32x16_t acc[2][2];
#pragma unroll
  for (int i = 0; i < 2; ++i)
#pragma unroll
    for (int j = 0; j < 2; ++j)
#pragma unroll
      for (int r = 0; r < 16; ++r)
        acc[i][j][r] = 0.f;

  // Staging: LDS chunk16 (row, c) stores global chunk (row, c ^ (row&7)).
  // Dest LDS is lane-contiguous (HW req); swizzle applied to global source.
  // Per-thread: row = tid>>3 (+32 per round), c = tid&7; since 32 ≡ 0 (mod 8)
  // the swizzled column (tid&7)^((tid>>3)&7) is round-invariant.
  const long ldA2 = (long)lda * 2, ldB2 = (long)ldb * 2;
  const int rowA = tid >> 3;
  const int csw  = (tid & 7) ^ (rowA & 7);
  const char* pA = (const char*)(Ab + (long)bm0 * lda) + (long)rowA * ldA2 + (csw << 4);
  const char* pB = (const char*)(Bb + (long)bn0 * ldb) + (long)rowA * ldB2 + (csw << 4);
  const int ldsbo = tid * 16;

  for (int k0 = 0; k0 < Keff; k0 += 64) {
    const long kb = (long)k0 * 2;
#pragma unroll
    for (int r = 0; r < 4; ++r)
      __builtin_amdgcn_global_load_lds(
          (const __attribute__((address_space(1))) unsigned int*)(pA + kb + (long)(r * 32) * ldA2),
          (__attribute__((address_space(3))) unsigned int*)((char*)lA + ldsbo + r * 4096), 16, 0, 0);
#pragma unroll
    for (int r = 0; r < 4; ++r)
      __builtin_amdgcn_global_load_lds(
          (const __attribute__((address_space(1))) unsigned int*)(pB + kb + (long)(r * 32) * ldB2),
          (__attribute__((address_space(3))) unsigned int*)((char*)lB + ldsbo + r * 4096), 16, 0, 0);
    __syncthreads();

    // logical k-chunk (s*2+kh) of row r lives at LDS chunk (s*2+kh)^(r&7)
#pragma unroll
    for (int s = 0; s < 4; ++s) {
      const int ck = ((s * 2 + kh) ^ swz) << 3;    // u16 offset in 64-elem row
      bf16x8_t a0 = *(const bf16x8_t*)&lA[(wm + ml) * 64 + ck];
      bf16x8_t a1 = *(const bf16x8_t*)&lA[(wm + 32 + ml) * 64 + ck];
      bf16x8_t b0 = *(const bf16x8_t*)&lB[(wn + ml) * 64 + ck];
      bf16x8_t b1 = *(const bf16x8_t*)&lB[(wn + 32 + ml) * 64 + ck];
      acc[0][0] = __builtin_amdgcn_mfma_f32_32x32x16_bf16(a0, b0, acc[0][0], 0, 0, 0);
      acc[0][1] = __builtin_amdgcn_mfma_f32_32x32x16_bf16(a0, b1, acc[0][1], 0, 0, 0);
      acc[1][0] = __builtin_amdgcn_mfma_f32_32x32x16_bf16(a1, b0, acc[1][0], 0, 0, 0);
      acc[1][1] = __builtin_amdgcn_mfma_f32_32x32x16_bf16(a1, b1, acc[1][1], 0, 0, 0);
    }
    __syncthreads();
  }

  // epilogue: 32x32 D layout col=lane&31, row=(reg&3)+8*(reg>>2)+4*(lane>>5)
  if (OUTMODE == 2 && bn0 >= 2048) {
    // V columns: write vT[batch][dcol][s] col-major, u16x4 over 4 consecutive rows
#pragma unroll
    for (int i = 0; i < 2; ++i) {
#pragma unroll
      for (int g = 0; g < 4; ++g) {
        const int rowb = bm0 + wm + i * 32 + g * 8 + kh * 4;  // 4 consecutive M rows
        const int b_  = rowb >> 11;                            // batch (t=2048)
        const int s_  = rowb & 2047;
#pragma unroll
        for (int j = 0; j < 2; ++j) {
          const int dcol = bn0 - 2048 + wn + j * 32 + ml;
          u16x4 o = {f2bf(acc[i][j][g * 4 + 0]), f2bf(acc[i][j][g * 4 + 1]),
                     f2bf(acc[i][j][g * 4 + 2]), f2bf(acc[i][j][g * 4 + 3])};
          *(u16x4*)&C2[(((long)b_ * 1024 + dcol) << 11) + s_] = o;
        }
      }
    }
    return;
  }
  u16*   Cb16 = (u16*)Cv + bz * sC;
  float* Cf32 = (float*)Cv + bz * sC;
#pragma unroll
  for (int i = 0; i < 2; ++i) {
#pragma unroll
    for (int j = 0; j < 2; ++j) {
#pragma unroll
      for (int reg = 0; reg < 16; ++reg) {
        const int row = bm0 + wm + i * 32 + (reg & 3) + 8 * (reg >> 2) + kh * 4;
        const int col = bn0 + wn + j * 32 + ml;
        float v = acc[i][j][reg];
        if (OUTMODE == 1) {
          Cf32[(long)row * ldc + col] = v + bias[col];
        } else {
          Cb16[(long)row * ldc + col] = f2bf(v);
        }
      }
    }
  }
}

// ---------------------------------------------------------------------------
__global__ __launch_bounds__(256)
void cvt_f32_bf16(const float* __restrict__ in, u16* __restrict__ out) {
  const int i = blockIdx.x * 256 + threadIdx.x;
  float4 v = ((const float4*)in)[i];
  u16x4 o = {f2bf(v.x), f2bf(v.y), f2bf(v.z), f2bf(v.w)};
  ((u16x4*)out)[i] = o;
}

// both weight transposes in one dispatch
__global__ __launch_bounds__(256)
void transpose_weights(const float* __restrict__ wqkv, u16* __restrict__ wqkvT,
                       const float* __restrict__ wproj, u16* __restrict__ wprojT) {
  const bool isq = blockIdx.x < 96;
  const float* in = isq ? wqkv : wproj;
  u16* out        = isq ? wqkvT : wprojT;
  const int C     = isq ? 3072 : 1024;
  const int c0 = (isq ? blockIdx.x : (blockIdx.x - 96)) * 32;
  const int r0 = blockIdx.y * 32;
  __shared__ float t[32][33];
  const int tx = threadIdx.x & 31, ty = threadIdx.x >> 5;
#pragma unroll
  for (int i = 0; i < 32; i += 8)
    t[ty + i][tx] = in[(long)(r0 + ty + i) * C + (c0 + tx)];
  __syncthreads();
#pragma unroll
  for (int i = 0; i < 32; i += 8)
    out[(long)(c0 + ty + i) * 1024 + (r0 + tx)] = f2bf(t[tx][ty + i]);
}

// ---------------------------------------------------------------------------
// Causal row softmax, in-place bf16 S -> P, register-resident.
// ---------------------------------------------------------------------------
__global__ __launch_bounds__(256)
void softmax_causal(u16* __restrict__ SP) {
  const int t = blockIdx.x;
  const int b = blockIdx.y;
  u16* row = SP + ((long)b * 2048 + t) * 2048;
  const int len = t + 1;
  const int end = ((t >> 7) + 1) << 7;   // 128-aligned
  const int tid = threadIdx.x;
  const int s0  = tid * 8;
  const float scale = 0.03125f;          // 1/sqrt(1024)
  __shared__ float red[8];

  float v[8];
  float lmax = -3.0e38f;
  if (s0 < end) {
    u16x4 u0 = *(const u16x4*)(row + s0);
    u16x4 u1 = *(const u16x4*)(row + s0 + 4);
    v[0] = bf2f(u0.x); v[1] = bf2f(u0.y); v[2] = bf2f(u0.z); v[3] = bf2f(u0.w);
    v[4] = bf2f(u1.x); v[5] = bf2f(u1.y); v[6] = bf2f(u1.z); v[7] = bf2f(u1.w);
#pragma unroll
    for (int e = 0; e < 8; ++e)
      if (s0 + e < len) { v[e] *= scale; lmax = fmaxf(lmax, v[e]); }
  }
#pragma unroll
  for (int o = 32; o; o >>= 1) lmax = fmaxf(lmax, __shfl_down(lmax, o));
  if ((tid & 63) == 0) red[tid >> 6] = lmax;
  __syncthreads();
  const float m = fmaxf(fmaxf(red[0], red[1]), fmaxf(red[2], red[3]));

  float lsum = 0.f;
  if (s0 < len) {
#pragma unroll
    for (int e = 0; e < 8; ++e)
      if (s0 + e < len) { v[e] = __expf(v[e] - m); lsum += v[e]; }
  }
#pragma unroll
  for (int o = 32; o; o >>= 1) lsum += __shfl_down(lsum, o);
  if ((tid & 63) == 0) red[4 + (tid >> 6)] = lsum;
  __syncthreads();
  const float inv = 1.0f / (red[4] + red[5] + red[6] + red[7]);

  if (s0 < end) {
    u16x4 o0, o1;
#pragma unroll
    for (int e = 0; e < 8; ++e) {
      const float ve = (s0 + e < len) ? v[e] * inv : 0.f;
      if (e < 4) ((u16*)&o0)[e] = f2bf(ve);
      else       ((u16*)&o1)[e - 4] = f2bf(ve);
    }
    *(u16x4*)(row + s0)     = o0;
    *(u16x4*)(row + s0 + 4) = o1;
  }
}

// ---------------------------------------------------------------------------
extern "C" void kernel_launch(void* const* d_in, const int* in_sizes, int n_in,
                              void* d_out, int out_size, void* d_ws, size_t ws_size,
                              hipStream_t stream) {
  (void)in_sizes; (void)n_in; (void)out_size; (void)ws_size;
  const float* x      = (const float*)d_in[0];
  const float* w_qkv  = (const float*)d_in[1];
  const float* w_proj = (const float*)d_in[2];
  const float* b_proj = (const float*)d_in[3];
  float* y = (float*)d_out;
  char*  ws = (char*)d_ws;

  // workspace layout (104 MB)
  u16* xbf    = (u16*)(ws);                  // 16 MB  x bf16; reused for attn_out
  u16* qk     = (u16*)(ws + (16l << 20));    // 32 MB  [4][2048][2048] bf16 (q | k)
  u16* wqkvT  = (u16*)(ws + (48l << 20));    //  6 MB  [3072,1024]
  u16* wprojT = (u16*)(ws + (54l << 20));    //  2 MB  [1024,1024]
  u16* vT     = (u16*)(ws + (56l << 20));    // 16 MB  [4][1024][2048]
  u16* SP     = (u16*)(ws + (72l << 20));    // 32 MB  [4][2048][2048] S->P in place
  u16* attn   = xbf;                         // lifetime-disjoint reuse

  // 1) x -> bf16
  cvt_f32_bf16<<<8192, 256, 0, stream>>>(x, xbf);
  // 2) weights -> transposed bf16 (one dispatch)
  transpose_weights<<<dim3(128, 32), 256, 0, stream>>>(w_qkv, wqkvT, w_proj, wprojT);
  // 3) qkv = x @ w_qkv : M=8192 N=3072 K=1024; q,k -> qk (ldc 2048), v -> vT fused
  gemm_bt<2, 0><<<dim3(24, 64, 1), 256, 0, stream>>>(
      xbf, wqkvT, qk, vT, nullptr, 1024, 1024, 1024, 2048, 0, 0, 0);
  // 4) S = q @ k^T, compact lower-triangular grid: 136 blocks x 4 batches
  gemm_bt<0, 1><<<dim3(136, 1, 4), 256, 0, stream>>>(
      qk, qk + 1024, SP, nullptr, nullptr, 1024, 2048, 2048, 2048,
      (long)2048 * 2048, (long)2048 * 2048, (long)2048 * 2048);
  // 5) P = softmax(S / 32), causal, in place, register-resident
  softmax_causal<<<dim3(2048, 4), 256, 0, stream>>>(SP);
  // 6) attn = P @ V : K_eff = bm0+128, longest blocks dispatched first
  gemm_bt<0, 2><<<dim3(8, 16, 4), 256, 0, stream>>>(
      SP, vT, attn, nullptr, nullptr, 2048, 2048, 2048, 1024,
      (long)2048 * 2048, (long)1024 * 2048, (long)2048 * 1024);
  // 7) y = attn @ w_proj + b_proj : fp32 out
  gemm_bt<1, 0><<<dim3(8, 64, 1), 256, 0, stream>>>(
      attn, wprojT, y, nullptr, b_proj, 1024, 1024, 1024, 1024, 0, 0, 0);
}